// Round 2
// baseline (538.950 us; speedup 1.0000x reference)
//
#include <hip/hip_runtime.h>

// MEASUREMENT PROBE — output identical to production kernel.
// Goal: the production maxpool kernel never appears in the rocprof top-5
// (all rows are 188 us harness fills), so its achieved BW is unknown.
// This probe adds 3 dense dummy read streams (shifted T/4, 2T/4, 3T/4 =
// 77/154/231 MB — re-touches separated by 308 MB aggregate > 256 MB L3,
// so they miss to HBM), ~4x-ing read traffic. That pushes kernel duration
// above the 188 us fill cutoff so it lands in the top-5 WITH ITS OWN
// hbm_gbps / VALUBusy / Occupancy row. Dummy loads kept live via
// asm volatile (no DCE), values never folded into the output.
//
// Decision rule (pre-committed):
//   implied_prod_time = 385.4 MB / probe_achieved_BW
//   <= ~70 us  -> revert to Round-0 kernel, declare roofline
//   else       -> attack the mechanism shown in the probe's counter row.

typedef float fvec4 __attribute__((ext_vector_type(4)));
typedef float fvec2 __attribute__((ext_vector_type(2)));

#define N_  16
#define C_  96
#define H_  224
#define W_  224
#define OH_ 112
#define OW_ 112
#define PAIRS_PER_ROW (OW_ / 2)   // 56

__device__ __forceinline__ const fvec4* pair_row0(const float* x, int t) {
    int p  = t % PAIRS_PER_ROW;        // pair index within output row
    int r  = t / PAIRS_PER_ROW;        // r = (n*C_ + c)*OH_ + oh
    int oh = r % OH_;
    int nc = r / OH_;
    return (const fvec4*)(x + ((size_t)nc * H_ + (size_t)(2 * oh)) * W_) + p;
}

__global__ __launch_bounds__(256) void maxpool2d_probe(
    const float* __restrict__ x, float* __restrict__ y, int total_pairs) {
    int t = blockIdx.x * blockDim.x + threadIdx.x;
    if (t >= total_pairs) return;

    const fvec4* row0 = pair_row0(x, t);
    const fvec4* row1 = row0 + (W_ / 4);

    fvec4 a = __builtin_nontemporal_load(row0);
    fvec4 b = __builtin_nontemporal_load(row1);

    // --- dummy far streams: same dense pattern, shifted by s*T/4 ---
    #pragma unroll
    for (int s = 1; s <= 3; ++s) {
        int tf = t + s * (total_pairs / 4);
        if (tf >= total_pairs) tf -= total_pairs;
        const fvec4* f0 = pair_row0(x, tf);
        const fvec4* f1 = f0 + (W_ / 4);
        fvec4 c = __builtin_nontemporal_load(f0);
        fvec4 d = __builtin_nontemporal_load(f1);
        asm volatile("" :: "v"(c.x), "v"(c.y), "v"(c.z), "v"(c.w),
                           "v"(d.x), "v"(d.y), "v"(d.z), "v"(d.w));
    }

    fvec2 o;
    o.x = fmaxf(fmaxf(a.x, a.y), fmaxf(b.x, b.y));
    o.y = fmaxf(fmaxf(a.z, a.w), fmaxf(b.z, b.w));

    int p = t % PAIRS_PER_ROW;
    int r = t / PAIRS_PER_ROW;
    fvec2* dst = (fvec2*)(y + (size_t)r * OW_) + p;
    __builtin_nontemporal_store(o, dst);
}

extern "C" void kernel_launch(void* const* d_in, const int* in_sizes, int n_in,
                              void* d_out, int out_size, void* d_ws, size_t ws_size,
                              hipStream_t stream) {
    const float* x = (const float*)d_in[0];
    float* y = (float*)d_out;

    const int total_pairs = N_ * C_ * OH_ * PAIRS_PER_ROW;  // 9,633,792
    const int block = 256;
    const int grid = (total_pairs + block - 1) / block;      // 37,632 blocks

    maxpool2d_probe<<<grid, block, 0, stream>>>(x, y, total_pairs);
}

// Round 3
// 399.672 us; speedup vs baseline: 1.3485x; 1.3485x over previous
//
#include <hip/hip_runtime.h>

// MaxPool2d: kernel 2x2, stride 2x2, VALID padding, NCHW fp32.
// x: (16, 96, 224, 224) -> y: (16, 96, 112, 112)
//
// ROOFLINE-VERIFIED REVERT (Round 2 probe decode):
//   - Probe with 4x read traffic delivered 6.32 TB/s to lanes (= achievable
//     ceiling); timestamp delta pins THIS kernel at ~68 us for 385.4 MB of
//     mandatory traffic = 5.7 TB/s = ~90% of the 6.3 TB/s copy ceiling,
//     consistent with 4:1 mixed read/write turnaround.
//   - Coalescing is perfect by construction: input read densely via dwordx4
//     (1 KiB/wave/instr), output written densely via dwordx2; zero reuse,
//     zero over-fetch. Remaining dur_us (~332 us) is harness re-poison fills.
//
// Streaming, zero reuse. Each thread produces 2 adjacent output columns:
//   - one dense fvec4 (dwordx4) load from input row 2*oh
//   - one dense fvec4 load from input row 2*oh+1
//   - one dense fvec2 (dwordx2) store
// All loads/stores non-temporal (read-once / write-once, skip cache pollution).

typedef float fvec4 __attribute__((ext_vector_type(4)));
typedef float fvec2 __attribute__((ext_vector_type(2)));

#define N_  16
#define C_  96
#define H_  224
#define W_  224
#define OH_ 112
#define OW_ 112
#define PAIRS_PER_ROW (OW_ / 2)   // 56

__global__ __launch_bounds__(256) void maxpool2d_k(
    const float* __restrict__ x, float* __restrict__ y, int total_pairs) {
    int t = blockIdx.x * blockDim.x + threadIdx.x;
    if (t >= total_pairs) return;

    int p  = t % PAIRS_PER_ROW;        // pair index within output row
    int r  = t / PAIRS_PER_ROW;        // r = (n*C_ + c)*OH_ + oh
    int oh = r % OH_;
    int nc = r / OH_;

    const fvec4* row0 = (const fvec4*)(x + ((size_t)nc * H_ + (size_t)(2 * oh)) * W_) + p;
    const fvec4* row1 = row0 + (W_ / 4);

    fvec4 a = __builtin_nontemporal_load(row0);
    fvec4 b = __builtin_nontemporal_load(row1);

    fvec2 o;
    o.x = fmaxf(fmaxf(a.x, a.y), fmaxf(b.x, b.y));
    o.y = fmaxf(fmaxf(a.z, a.w), fmaxf(b.z, b.w));

    fvec2* dst = (fvec2*)(y + (size_t)r * OW_) + p;
    __builtin_nontemporal_store(o, dst);
}

extern "C" void kernel_launch(void* const* d_in, const int* in_sizes, int n_in,
                              void* d_out, int out_size, void* d_ws, size_t ws_size,
                              hipStream_t stream) {
    const float* x = (const float*)d_in[0];
    float* y = (float*)d_out;

    const int total_pairs = N_ * C_ * OH_ * PAIRS_PER_ROW;  // 9,633,792
    const int block = 256;
    const int grid = (total_pairs + block - 1) / block;      // 37,632 blocks

    maxpool2d_k<<<grid, block, 0, stream>>>(x, y, total_pairs);
}